// Round 4
// baseline (827.488 us; speedup 1.0000x reference)
//
#include <hip/hip_runtime.h>
#include <hip/hip_bf16.h>
#include <cstdint>

// ---------------- CSR build ----------------
// NOTE: harness passes integer inputs as int32.

__global__ __launch_bounds__(256) void k_init(int* cnt, int* cursor, int n) {
  int i = blockIdx.x * 256 + threadIdx.x;
  if (i < n) { cnt[i] = 1; cursor[i] = 0; }  // cnt starts at 1 for the self-loop
}

__global__ __launch_bounds__(256) void k_count(const int* __restrict__ ei,
                                               int* __restrict__ cnt, int E) {
  int e = blockIdx.x * 256 + threadIdx.x;
  if (e < E) atomicAdd(&cnt[ei[E + e]], 1);
}

__global__ __launch_bounds__(1024) void k_bsum(const int* __restrict__ cnt,
                                               int* __restrict__ bsum, int n) {
  __shared__ int ws_[16];
  int i = blockIdx.x * 1024 + threadIdx.x;
  int v = (i < n) ? cnt[i] : 0;
#pragma unroll
  for (int d = 1; d < 64; d <<= 1) v += __shfl_xor(v, d);
  int lane = threadIdx.x & 63, wid = threadIdx.x >> 6;
  if (lane == 0) ws_[wid] = v;
  __syncthreads();
  if (threadIdx.x == 0) {
    int s = 0;
#pragma unroll
    for (int j = 0; j < 16; ++j) s += ws_[j];
    bsum[blockIdx.x] = s;
  }
}

// single-wave exclusive scan of block sums (nb <= 64 for N=50000)
__global__ __launch_bounds__(64) void k_scanb(int* bsum, int* off, int nb, int n) {
  int t = threadIdx.x;
  int v = (t < nb) ? bsum[t] : 0;
  int orig = v;
#pragma unroll
  for (int d = 1; d < 64; d <<= 1) {
    int u = __shfl_up(v, d, 64);
    if (t >= d) v += u;
  }
  if (t < nb) bsum[t] = v - orig;   // exclusive block offset
  if (t == 63) off[n] = v;          // grand total
}

__global__ __launch_bounds__(1024) void k_scanc(const int* __restrict__ cnt,
                                                const int* __restrict__ bsum,
                                                int* __restrict__ off, int n) {
  __shared__ int wsum[16];
  int i = blockIdx.x * 1024 + threadIdx.x;
  int v = (i < n) ? cnt[i] : 0;
  int orig = v;
  int lane = threadIdx.x & 63, wid = threadIdx.x >> 6;
#pragma unroll
  for (int d = 1; d < 64; d <<= 1) {
    int u = __shfl_up(v, d, 64);
    if (lane >= d) v += u;
  }
  if (lane == 63) wsum[wid] = v;
  __syncthreads();
  if (wid == 0) {
    int s = (lane < 16) ? wsum[lane] : 0;
#pragma unroll
    for (int d = 1; d < 16; d <<= 1) {
      int u = __shfl_up(s, d, 64);
      if (lane >= d) s += u;
    }
    if (lane < 16) wsum[lane] = s;
  }
  __syncthreads();
  if (wid > 0) v += wsum[wid - 1];
  if (i < n) off[i] = bsum[blockIdx.x] + v - orig;  // exclusive
}

__global__ __launch_bounds__(256) void k_scatter(const int* __restrict__ ei,
                                                 const int* __restrict__ off,
                                                 int* __restrict__ cursor,
                                                 int* __restrict__ adj, int E, int n) {
  int idx = blockIdx.x * 256 + threadIdx.x;
  if (idx < E) {
    int s = ei[idx];
    int d = ei[E + idx];
    int pos = off[d] + atomicAdd(&cursor[d], 1);
    adj[pos] = s;
  } else if (idx < E + n) {
    int i = idx - E;
    int pos = off[i] + atomicAdd(&cursor[i], 1);
    adj[pos] = i;  // self loop
  }
}

// ---------------- GEMM1: h1 = x @ W1, fused alpha_src/alpha_dst ----------------

__global__ __launch_bounds__(256) void k_gemm1(const float* __restrict__ x,
                                               const float* __restrict__ W,
                                               const float* __restrict__ a_src,
                                               const float* __restrict__ a_dst,
                                               float* __restrict__ h1,
                                               float* __restrict__ as1,
                                               float* __restrict__ ad1, int n) {
  __shared__ float xs[64][132];       // 33.8 KB (132 floats = 33x16B, float4-aligned rows)
  __shared__ float wbuf[32 * 128];    // 16 KB: one 32-row K-chunk of W
  int t = threadIdx.x;
  int tr = t >> 5, tc = t & 31;
  int head = tc >> 3;
  float a_s[4], a_d[4];
#pragma unroll
  for (int ci = 0; ci < 4; ++ci) {
    int dcol = (tc * 4 + ci) & 31;
    a_s[ci] = a_src[head * 32 + dcol];
    a_d[ci] = a_dst[head * 32 + dcol];
  }
  int ntiles = (n + 63) >> 6;
  for (int tile = blockIdx.x; tile < ntiles; tile += gridDim.x) {
    int row0 = tile << 6;
    __syncthreads();
#pragma unroll
    for (int rr = 0; rr < 64; rr += 8) {
      int r = rr + tr;
      int gr = row0 + r;
      float4 v = make_float4(0.f, 0.f, 0.f, 0.f);
      if (gr < n) v = *(const float4*)&x[(size_t)gr * 128 + tc * 4];
      *(float4*)&xs[r][tc * 4] = v;
    }
    float4 acc[8];
#pragma unroll
    for (int ri = 0; ri < 8; ++ri) acc[ri] = make_float4(0.f, 0.f, 0.f, 0.f);
#pragma unroll
    for (int kt = 0; kt < 4; ++kt) {
      __syncthreads();
#pragma unroll
      for (int i = t * 4; i < 32 * 128; i += 1024)
        *(float4*)&wbuf[i] = *(const float4*)&W[kt * 32 * 128 + i];
      __syncthreads();
      for (int k0 = 0; k0 < 8; ++k0) {
        float4 xv[8];
#pragma unroll
        for (int ri = 0; ri < 8; ++ri)
          xv[ri] = *(float4*)&xs[tr * 8 + ri][kt * 32 + k0 * 4];
#pragma unroll
        for (int kk = 0; kk < 4; ++kk) {
          float4 wv = *(float4*)&wbuf[(k0 * 4 + kk) * 128 + tc * 4];
#pragma unroll
          for (int ri = 0; ri < 8; ++ri) {
            float xvv = kk == 0 ? xv[ri].x : kk == 1 ? xv[ri].y
                       : kk == 2 ? xv[ri].z : xv[ri].w;
            acc[ri].x += xvv * wv.x;
            acc[ri].y += xvv * wv.y;
            acc[ri].z += xvv * wv.z;
            acc[ri].w += xvv * wv.w;
          }
        }
      }
    }
#pragma unroll
    for (int ri = 0; ri < 8; ++ri) {
      int gr = row0 + tr * 8 + ri;
      float ps = acc[ri].x * a_s[0] + acc[ri].y * a_s[1] +
                 acc[ri].z * a_s[2] + acc[ri].w * a_s[3];
      float pd = acc[ri].x * a_d[0] + acc[ri].y * a_d[1] +
                 acc[ri].z * a_d[2] + acc[ri].w * a_d[3];
      ps += __shfl_xor(ps, 1); ps += __shfl_xor(ps, 2); ps += __shfl_xor(ps, 4);
      pd += __shfl_xor(pd, 1); pd += __shfl_xor(pd, 2); pd += __shfl_xor(pd, 4);
      if (gr < n) {
        *(float4*)&h1[(size_t)gr * 128 + tc * 4] = acc[ri];
        if ((tc & 7) == 0) {
          as1[gr * 4 + head] = ps;
          ad1[gr * 4 + head] = pd;
        }
      }
    }
  }
}

// ---------------- conv1 aggregation: 4 nodes/wave, 16 lanes/node ----------------
// phase 2: per 8-edge chunk, the 16 lanes (= 4 edges x 4 heads) precompute all
// softmax weights in parallel; serial consume loop is pure shfl + h1-gather + FMA.

__global__ __launch_bounds__(256) void k_conv1(const int* __restrict__ off,
                                               const int* __restrict__ adj,
                                               const float* __restrict__ h1,
                                               const float* __restrict__ as1,
                                               const float* __restrict__ ad1,
                                               const float* __restrict__ b1,
                                               float* __restrict__ x2, int n) {
  int wid = (blockIdx.x * 256 + threadIdx.x) >> 6;  // global wave id
  int lane = threadIdx.x & 63;
  int grp = lane >> 4;       // node slot within wave
  int l16 = lane & 15;
  int node = wid * 4 + grp;
  bool active = node < n;
  int beg = 0, end = 0;
  float4 adv = make_float4(0.f, 0.f, 0.f, 0.f);
  if (active) {
    beg = off[node];
    end = off[node + 1];
    adv = *(const float4*)&ad1[node * 4];
  }
  // phase 1: online softmax (m,z) per head; lanes l16 stride 16 over edges
  float m0 = -1e30f, m1 = -1e30f, m2 = -1e30f, m3 = -1e30f;
  float z0 = 0.f, z1 = 0.f, z2 = 0.f, z3 = 0.f;
  for (int e = beg + l16; e < end; e += 16) {
    int s = adj[e];
    float4 av = *(const float4*)&as1[s * 4];
    float v, nm;
    v = av.x + adv.x; v = v > 0.f ? v : 0.2f * v;
    nm = fmaxf(m0, v); z0 = z0 * __expf(m0 - nm) + __expf(v - nm); m0 = nm;
    v = av.y + adv.y; v = v > 0.f ? v : 0.2f * v;
    nm = fmaxf(m1, v); z1 = z1 * __expf(m1 - nm) + __expf(v - nm); m1 = nm;
    v = av.z + adv.z; v = v > 0.f ? v : 0.2f * v;
    nm = fmaxf(m2, v); z2 = z2 * __expf(m2 - nm) + __expf(v - nm); m2 = nm;
    v = av.w + adv.w; v = v > 0.f ? v : 0.2f * v;
    nm = fmaxf(m3, v); z3 = z3 * __expf(m3 - nm) + __expf(v - nm); m3 = nm;
  }
#pragma unroll
  for (int d = 1; d < 16; d <<= 1) {  // butterfly within 16-lane group
    float om, oz, nm;
    om = __shfl_xor(m0, d); oz = __shfl_xor(z0, d);
    nm = fmaxf(m0, om); z0 = z0 * __expf(m0 - nm) + oz * __expf(om - nm); m0 = nm;
    om = __shfl_xor(m1, d); oz = __shfl_xor(z1, d);
    nm = fmaxf(m1, om); z1 = z1 * __expf(m1 - nm) + oz * __expf(om - nm); m1 = nm;
    om = __shfl_xor(m2, d); oz = __shfl_xor(z2, d);
    nm = fmaxf(m2, om); z2 = z2 * __expf(m2 - nm) + oz * __expf(om - nm); m2 = nm;
    om = __shfl_xor(m3, d); oz = __shfl_xor(z3, d);
    nm = fmaxf(m3, om); z3 = z3 * __expf(m3 - nm) + oz * __expf(om - nm); m3 = nm;
  }
  // phase 2
  int hh = (l16 >> 2) & 3;   // head for this lane's channels AND its weight-compute slot
  int esub = l16 & 3;        // edge slot within chunk
  float mm  = hh == 0 ? m0 : hh == 1 ? m1 : hh == 2 ? m2 : m3;
  float zz  = hh == 0 ? z0 : hh == 1 ? z1 : hh == 2 ? z2 : z3;
  float adh = hh == 0 ? adv.x : hh == 1 ? adv.y : hh == 2 ? adv.z : adv.w;
  float inv = 1.0f / (zz + 1e-16f);
  int c0 = l16 * 8;
  float4 acc0 = make_float4(0.f, 0.f, 0.f, 0.f);
  float4 acc1 = make_float4(0.f, 0.f, 0.f, 0.f);
  for (int e0 = beg; e0 < end; e0 += 8) {
    // 16-wide weight precompute for edges e0+esub and e0+4+esub at head hh
    int sa = 0, sb = 0;
    float wa = 0.f, wb = 0.f;
    int ea = e0 + esub, eb = e0 + 4 + esub;
    if (ea < end) {
      sa = adj[ea];
      float v = as1[sa * 4 + hh] + adh;
      v = v > 0.f ? v : 0.2f * v;
      wa = __expf(v - mm) * inv;
    }
    if (eb < end) {
      sb = adj[eb];
      float v = as1[sb * 4 + hh] + adh;
      v = v > 0.f ? v : 0.2f * v;
      wb = __expf(v - mm) * inv;
    }
    // consume 8 edges; src/weight broadcast from lane (lane&60)|j
#pragma unroll
    for (int j = 0; j < 8; ++j) {
      int sl = (lane & 60) | (j & 3);
      int s = (j < 4) ? __shfl(sa, sl) : __shfl(sb, sl);
      float w = (j < 4) ? __shfl(wa, sl) : __shfl(wb, sl);
      if (e0 + j < end) {  // uniform within the 16-lane group
        const float4* p = (const float4*)&h1[(size_t)s * 128 + c0];
        float4 a = p[0], b = p[1];
        acc0.x += w * a.x; acc0.y += w * a.y; acc0.z += w * a.z; acc0.w += w * a.w;
        acc1.x += w * b.x; acc1.y += w * b.y; acc1.z += w * b.z; acc1.w += w * b.w;
      }
    }
  }
  if (active) {
    float4 bb0 = *(const float4*)&b1[c0];
    float4 bb1 = *(const float4*)&b1[c0 + 4];
    float o[8] = {acc0.x + bb0.x, acc0.y + bb0.y, acc0.z + bb0.z, acc0.w + bb0.w,
                  acc1.x + bb1.x, acc1.y + bb1.y, acc1.z + bb1.z, acc1.w + bb1.w};
#pragma unroll
    for (int j = 0; j < 8; ++j) o[j] = o[j] > 0.f ? o[j] : __expf(o[j]) - 1.f;  // ELU
    *(float4*)&x2[(size_t)node * 128 + c0]     = make_float4(o[0], o[1], o[2], o[3]);
    *(float4*)&x2[(size_t)node * 128 + c0 + 4] = make_float4(o[4], o[5], o[6], o[7]);
  }
}

// ---------------- GEMM2: 4 rows/wave, 16 lanes/row ----------------

__global__ __launch_bounds__(256) void k_gemm2(const float* __restrict__ x2,
                                               const float* __restrict__ W2,
                                               const float* __restrict__ a_src,
                                               const float* __restrict__ a_dst,
                                               float* __restrict__ h2,
                                               float* __restrict__ as2,
                                               float* __restrict__ ad2, int n) {
  int wid = (blockIdx.x * 256 + threadIdx.x) >> 6;
  int lane = threadIdx.x & 63;
  int grp = lane >> 4, l16 = lane & 15;
  int row = wid * 4 + grp;
  if (row >= n) return;
  const float4* xp = (const float4*)&x2[(size_t)row * 128 + l16 * 8];
  float4 xa = xp[0], xb = xp[1];
  const float* wr = &W2[l16 * 8 * 10];
  float acc[10];
#pragma unroll
  for (int c = 0; c < 10; ++c) {
    acc[c] = xa.x * wr[c]      + xa.y * wr[10 + c] + xa.z * wr[20 + c] +
             xa.w * wr[30 + c] + xb.x * wr[40 + c] + xb.y * wr[50 + c] +
             xb.z * wr[60 + c] + xb.w * wr[70 + c];
  }
#pragma unroll
  for (int c = 0; c < 10; ++c) {
#pragma unroll
    for (int d = 1; d < 16; d <<= 1) acc[c] += __shfl_xor(acc[c], d);
  }
  if (l16 == 0) {
    float s = 0.f, ds = 0.f;
#pragma unroll
    for (int c = 0; c < 10; ++c) {
      h2[(size_t)row * 10 + c] = acc[c];
      s += acc[c] * a_src[c];
      ds += acc[c] * a_dst[c];
    }
    as2[row] = s;
    ad2[row] = ds;
  }
}

// ---------------- conv2 aggregation: 4 nodes per wave, 16 lanes per node ----------------

__global__ __launch_bounds__(256) void k_conv2(const int* __restrict__ off,
                                               const int* __restrict__ adj,
                                               const float* __restrict__ h2,
                                               const float* __restrict__ as2,
                                               const float* __restrict__ ad2,
                                               const float* __restrict__ b2,
                                               float* __restrict__ out, int n) {
  int wid = (blockIdx.x * 256 + threadIdx.x) >> 6;
  int lane = threadIdx.x & 63;
  int grp = lane >> 4;
  int l16 = lane & 15;
  int node = wid * 4 + grp;
  bool active = node < n;
  int beg = 0, end = 0;
  float adv = 0.f;
  if (active) {
    beg = off[node];
    end = off[node + 1];
    adv = ad2[node];
  }
  float m = -1e30f, z = 0.f;
  for (int e = beg + l16; e < end; e += 16) {
    int s = adj[e];
    float v = as2[s] + adv;
    v = v > 0.f ? v : 0.2f * v;
    float nm = fmaxf(m, v);
    z = z * __expf(m - nm) + __expf(v - nm);
    m = nm;
  }
#pragma unroll
  for (int d = 1; d < 16; d <<= 1) {
    float om = __shfl_xor(m, d), oz = __shfl_xor(z, d);
    float nm = fmaxf(m, om);
    z = z * __expf(m - nm) + oz * __expf(om - nm);
    m = nm;
  }
  float inv = 1.0f / (z + 1e-16f);
  float acc[10] = {};
  for (int e = beg + l16; e < end; e += 16) {
    int s = adj[e];
    float v = as2[s] + adv;
    v = v > 0.f ? v : 0.2f * v;
    float wgt = __expf(v - m) * inv;
    const float2* hp = (const float2*)&h2[(size_t)s * 10];
    float2 h01 = hp[0], h23 = hp[1], h45 = hp[2], h67 = hp[3], h89 = hp[4];
    acc[0] += wgt * h01.x; acc[1] += wgt * h01.y;
    acc[2] += wgt * h23.x; acc[3] += wgt * h23.y;
    acc[4] += wgt * h45.x; acc[5] += wgt * h45.y;
    acc[6] += wgt * h67.x; acc[7] += wgt * h67.y;
    acc[8] += wgt * h89.x; acc[9] += wgt * h89.y;
  }
#pragma unroll
  for (int c = 0; c < 10; ++c) {
#pragma unroll
    for (int d = 1; d < 16; d <<= 1) acc[c] += __shfl_xor(acc[c], d);
  }
  if (active && l16 == 0) {
#pragma unroll
    for (int c = 0; c < 10; ++c) out[(size_t)node * 10 + c] = acc[c] + b2[c];
  }
}

// ---------------- launch ----------------

extern "C" void kernel_launch(void* const* d_in, const int* in_sizes, int n_in,
                              void* d_out, int out_size, void* d_ws, size_t ws_size,
                              hipStream_t stream) {
  const float* x      = (const float*)d_in[0];
  const int* ei       = (const int*)d_in[1];
  const float* W1     = (const float*)d_in[2];
  const float* a_src1 = (const float*)d_in[3];
  const float* a_dst1 = (const float*)d_in[4];
  const float* b1     = (const float*)d_in[5];
  const float* W2     = (const float*)d_in[6];
  const float* a_src2 = (const float*)d_in[7];
  const float* a_dst2 = (const float*)d_in[8];
  const float* b2     = (const float*)d_in[9];
  float* out = (float*)d_out;
  const int N = in_sizes[0] / 128;
  const int E = in_sizes[1] / 2;

  char* ws = (char*)d_ws;
  size_t o = 0;
  auto alloc = [&](size_t bytes) -> void* {
    void* p = ws + o;
    o += (bytes + 255) & ~(size_t)255;
    return p;
  };
  int* cnt    = (int*)alloc((size_t)N * 4);
  int* cursor = (int*)alloc((size_t)N * 4);
  int* offs   = (int*)alloc((size_t)(N + 1) * 4);
  int* bsum   = (int*)alloc(1024 * 4);
  int* adj    = (int*)alloc((size_t)(E + N) * 4);
  float* h1   = (float*)alloc((size_t)N * 128 * 4);
  float* a_s1 = (float*)alloc((size_t)N * 4 * 4);
  float* a_d1 = (float*)alloc((size_t)N * 4 * 4);
  float* x2   = (float*)alloc((size_t)N * 128 * 4);
  float* h2   = (float*)alloc((size_t)N * 10 * 4);
  float* a_s2 = (float*)alloc((size_t)N * 4);
  float* a_d2 = (float*)alloc((size_t)N * 4);

  int nb = (N + 1023) / 1024;
  k_init<<<(N + 255) / 256, 256, 0, stream>>>(cnt, cursor, N);
  k_count<<<(E + 255) / 256, 256, 0, stream>>>(ei, cnt, E);
  k_bsum<<<nb, 1024, 0, stream>>>(cnt, bsum, N);
  k_scanb<<<1, 64, 0, stream>>>(bsum, offs, nb, N);
  k_scanc<<<nb, 1024, 0, stream>>>(cnt, bsum, offs, N);
  k_scatter<<<(E + N + 255) / 256, 256, 0, stream>>>(ei, offs, cursor, adj, E, N);
  int g1 = (N + 63) / 64;  // one block per 64-row tile
  k_gemm1<<<g1, 256, 0, stream>>>(x, W1, a_src1, a_dst1, h1, a_s1, a_d1, N);
  k_conv1<<<(N + 15) / 16, 256, 0, stream>>>(offs, adj, h1, a_s1, a_d1, b1, x2, N);
  k_gemm2<<<(N + 15) / 16, 256, 0, stream>>>(x2, W2, a_src2, a_dst2, h2, a_s2, a_d2, N);
  k_conv2<<<(N + 15) / 16, 256, 0, stream>>>(offs, adj, h2, a_s2, a_d2, b2, out, N);
}

// Round 5
// 248.695 us; speedup vs baseline: 3.3273x; 3.3273x over previous
//
#include <hip/hip_runtime.h>
#include <hip/hip_bf16.h>
#include <cstdint>

// ---------------- CSR build ----------------
// NOTE: harness passes integer inputs as int32.

__global__ __launch_bounds__(256) void k_init(int* cnt, int* cursor, int n) {
  int i = blockIdx.x * 256 + threadIdx.x;
  if (i < n) { cnt[i] = 1; cursor[i] = 0; }  // cnt starts at 1 for the self-loop
}

__global__ __launch_bounds__(256) void k_count(const int* __restrict__ ei,
                                               int* __restrict__ cnt, int E) {
  int e = blockIdx.x * 256 + threadIdx.x;
  if (e < E) atomicAdd(&cnt[ei[E + e]], 1);
}

__global__ __launch_bounds__(1024) void k_bsum(const int* __restrict__ cnt,
                                               int* __restrict__ bsum, int n) {
  __shared__ int ws_[16];
  int i = blockIdx.x * 1024 + threadIdx.x;
  int v = (i < n) ? cnt[i] : 0;
#pragma unroll
  for (int d = 1; d < 64; d <<= 1) v += __shfl_xor(v, d);
  int lane = threadIdx.x & 63, wid = threadIdx.x >> 6;
  if (lane == 0) ws_[wid] = v;
  __syncthreads();
  if (threadIdx.x == 0) {
    int s = 0;
#pragma unroll
    for (int j = 0; j < 16; ++j) s += ws_[j];
    bsum[blockIdx.x] = s;
  }
}

// single-wave exclusive scan of block sums (nb <= 64 for N=50000)
__global__ __launch_bounds__(64) void k_scanb(int* bsum, int* off, int nb, int n) {
  int t = threadIdx.x;
  int v = (t < nb) ? bsum[t] : 0;
  int orig = v;
#pragma unroll
  for (int d = 1; d < 64; d <<= 1) {
    int u = __shfl_up(v, d, 64);
    if (t >= d) v += u;
  }
  if (t < nb) bsum[t] = v - orig;   // exclusive block offset
  if (t == 63) off[n] = v;          // grand total
}

__global__ __launch_bounds__(1024) void k_scanc(const int* __restrict__ cnt,
                                                const int* __restrict__ bsum,
                                                int* __restrict__ off, int n) {
  __shared__ int wsum[16];
  int i = blockIdx.x * 1024 + threadIdx.x;
  int v = (i < n) ? cnt[i] : 0;
  int orig = v;
  int lane = threadIdx.x & 63, wid = threadIdx.x >> 6;
#pragma unroll
  for (int d = 1; d < 64; d <<= 1) {
    int u = __shfl_up(v, d, 64);
    if (lane >= d) v += u;
  }
  if (lane == 63) wsum[wid] = v;
  __syncthreads();
  if (wid == 0) {
    int s = (lane < 16) ? wsum[lane] : 0;
#pragma unroll
    for (int d = 1; d < 16; d <<= 1) {
      int u = __shfl_up(s, d, 64);
      if (lane >= d) s += u;
    }
    if (lane < 16) wsum[lane] = s;
  }
  __syncthreads();
  if (wid > 0) v += wsum[wid - 1];
  if (i < n) off[i] = bsum[blockIdx.x] + v - orig;  // exclusive
}

__global__ __launch_bounds__(256) void k_scatter(const int* __restrict__ ei,
                                                 const int* __restrict__ off,
                                                 int* __restrict__ cursor,
                                                 int* __restrict__ adj, int E, int n) {
  int idx = blockIdx.x * 256 + threadIdx.x;
  if (idx < E) {
    int s = ei[idx];
    int d = ei[E + idx];
    int pos = off[d] + atomicAdd(&cursor[d], 1);
    adj[pos] = s;
  } else if (idx < E + n) {
    int i = idx - E;
    int pos = off[i] + atomicAdd(&cursor[i], 1);
    adj[pos] = i;  // self loop
  }
}

// ---------------- GEMM1: h1 = x @ W1, fused alpha_src/alpha_dst ----------------
// R3-proven structure: scalar xs reads, acc[8][4] floats, unroll-8 K loop.
// (R4's float4-xs variant fully unrolled and spilled at VGPR=256 — do not revisit.)

__global__ __launch_bounds__(256) void k_gemm1(const float* __restrict__ x,
                                               const float* __restrict__ W,
                                               const float* __restrict__ a_src,
                                               const float* __restrict__ a_dst,
                                               float* __restrict__ h1,
                                               float* __restrict__ as1,
                                               float* __restrict__ ad1, int n) {
  __shared__ float xs[64][132];       // 33.8 KB (padded)
  __shared__ float wbuf[32 * 128];    // 16 KB: one 32-row K-chunk of W
  int t = threadIdx.x;
  int tr = t >> 5, tc = t & 31;
  int head = tc >> 3;
  float a_s[4], a_d[4];
#pragma unroll
  for (int ci = 0; ci < 4; ++ci) {
    int dcol = (tc * 4 + ci) & 31;
    a_s[ci] = a_src[head * 32 + dcol];
    a_d[ci] = a_dst[head * 32 + dcol];
  }
  int ntiles = (n + 63) >> 6;
  for (int tile = blockIdx.x; tile < ntiles; tile += gridDim.x) {
    int row0 = tile << 6;
    __syncthreads();
#pragma unroll
    for (int rr = 0; rr < 64; rr += 8) {
      int r = rr + tr;
      int gr = row0 + r;
      float4 v = make_float4(0.f, 0.f, 0.f, 0.f);
      if (gr < n) v = *(const float4*)&x[(size_t)gr * 128 + tc * 4];
      *(float4*)&xs[r][tc * 4] = v;
    }
    float acc[8][4] = {};
#pragma unroll
    for (int kt = 0; kt < 4; ++kt) {
      __syncthreads();
#pragma unroll
      for (int i = t * 4; i < 32 * 128; i += 1024)
        *(float4*)&wbuf[i] = *(const float4*)&W[kt * 32 * 128 + i];
      __syncthreads();
#pragma unroll 8
      for (int k = 0; k < 32; ++k) {
        float4 wv = *(float4*)&wbuf[k * 128 + tc * 4];
#pragma unroll
        for (int ri = 0; ri < 8; ++ri) {
          float xv = xs[tr * 8 + ri][kt * 32 + k];
          acc[ri][0] += xv * wv.x;
          acc[ri][1] += xv * wv.y;
          acc[ri][2] += xv * wv.z;
          acc[ri][3] += xv * wv.w;
        }
      }
    }
#pragma unroll
    for (int ri = 0; ri < 8; ++ri) {
      int gr = row0 + tr * 8 + ri;
      float ps = acc[ri][0] * a_s[0] + acc[ri][1] * a_s[1] +
                 acc[ri][2] * a_s[2] + acc[ri][3] * a_s[3];
      float pd = acc[ri][0] * a_d[0] + acc[ri][1] * a_d[1] +
                 acc[ri][2] * a_d[2] + acc[ri][3] * a_d[3];
      ps += __shfl_xor(ps, 1); ps += __shfl_xor(ps, 2); ps += __shfl_xor(ps, 4);
      pd += __shfl_xor(pd, 1); pd += __shfl_xor(pd, 2); pd += __shfl_xor(pd, 4);
      if (gr < n) {
        *(float4*)&h1[(size_t)gr * 128 + tc * 4] =
            make_float4(acc[ri][0], acc[ri][1], acc[ri][2], acc[ri][3]);
        if ((tc & 7) == 0) {
          as1[gr * 4 + head] = ps;
          ad1[gr * 4 + head] = pd;
        }
      }
    }
  }
}

// ---------------- conv1 aggregation: 4 nodes/wave, 16 lanes/node ----------------
// phase 2: per 8-edge chunk, the 16 lanes (= 4 edges x 4 heads) precompute all
// softmax weights in parallel; serial consume loop is pure shfl + h1-gather + FMA.

__global__ __launch_bounds__(256) void k_conv1(const int* __restrict__ off,
                                               const int* __restrict__ adj,
                                               const float* __restrict__ h1,
                                               const float* __restrict__ as1,
                                               const float* __restrict__ ad1,
                                               const float* __restrict__ b1,
                                               float* __restrict__ x2, int n) {
  int wid = (blockIdx.x * 256 + threadIdx.x) >> 6;  // global wave id
  int lane = threadIdx.x & 63;
  int grp = lane >> 4;       // node slot within wave
  int l16 = lane & 15;
  int node = wid * 4 + grp;
  bool active = node < n;
  int beg = 0, end = 0;
  float4 adv = make_float4(0.f, 0.f, 0.f, 0.f);
  if (active) {
    beg = off[node];
    end = off[node + 1];
    adv = *(const float4*)&ad1[node * 4];
  }
  // phase 1: online softmax (m,z) per head; lanes l16 stride 16 over edges
  float m0 = -1e30f, m1 = -1e30f, m2 = -1e30f, m3 = -1e30f;
  float z0 = 0.f, z1 = 0.f, z2 = 0.f, z3 = 0.f;
  for (int e = beg + l16; e < end; e += 16) {
    int s = adj[e];
    float4 av = *(const float4*)&as1[s * 4];
    float v, nm;
    v = av.x + adv.x; v = v > 0.f ? v : 0.2f * v;
    nm = fmaxf(m0, v); z0 = z0 * __expf(m0 - nm) + __expf(v - nm); m0 = nm;
    v = av.y + adv.y; v = v > 0.f ? v : 0.2f * v;
    nm = fmaxf(m1, v); z1 = z1 * __expf(m1 - nm) + __expf(v - nm); m1 = nm;
    v = av.z + adv.z; v = v > 0.f ? v : 0.2f * v;
    nm = fmaxf(m2, v); z2 = z2 * __expf(m2 - nm) + __expf(v - nm); m2 = nm;
    v = av.w + adv.w; v = v > 0.f ? v : 0.2f * v;
    nm = fmaxf(m3, v); z3 = z3 * __expf(m3 - nm) + __expf(v - nm); m3 = nm;
  }
#pragma unroll
  for (int d = 1; d < 16; d <<= 1) {  // butterfly within 16-lane group
    float om, oz, nm;
    om = __shfl_xor(m0, d); oz = __shfl_xor(z0, d);
    nm = fmaxf(m0, om); z0 = z0 * __expf(m0 - nm) + oz * __expf(om - nm); m0 = nm;
    om = __shfl_xor(m1, d); oz = __shfl_xor(z1, d);
    nm = fmaxf(m1, om); z1 = z1 * __expf(m1 - nm) + oz * __expf(om - nm); m1 = nm;
    om = __shfl_xor(m2, d); oz = __shfl_xor(z2, d);
    nm = fmaxf(m2, om); z2 = z2 * __expf(m2 - nm) + oz * __expf(om - nm); m2 = nm;
    om = __shfl_xor(m3, d); oz = __shfl_xor(z3, d);
    nm = fmaxf(m3, om); z3 = z3 * __expf(m3 - nm) + oz * __expf(om - nm); m3 = nm;
  }
  // phase 2
  int hh = (l16 >> 2) & 3;   // head for this lane's channels AND its weight-compute slot
  int esub = l16 & 3;        // edge slot within chunk
  float mm  = hh == 0 ? m0 : hh == 1 ? m1 : hh == 2 ? m2 : m3;
  float zz  = hh == 0 ? z0 : hh == 1 ? z1 : hh == 2 ? z2 : z3;
  float adh = hh == 0 ? adv.x : hh == 1 ? adv.y : hh == 2 ? adv.z : adv.w;
  float inv = 1.0f / (zz + 1e-16f);
  int c0 = l16 * 8;
  float4 acc0 = make_float4(0.f, 0.f, 0.f, 0.f);
  float4 acc1 = make_float4(0.f, 0.f, 0.f, 0.f);
  for (int e0 = beg; e0 < end; e0 += 8) {
    // 16-wide weight precompute for edges e0+esub and e0+4+esub at head hh
    int sa = 0, sb = 0;
    float wa = 0.f, wb = 0.f;
    int ea = e0 + esub, eb = e0 + 4 + esub;
    if (ea < end) {
      sa = adj[ea];
      float v = as1[sa * 4 + hh] + adh;
      v = v > 0.f ? v : 0.2f * v;
      wa = __expf(v - mm) * inv;
    }
    if (eb < end) {
      sb = adj[eb];
      float v = as1[sb * 4 + hh] + adh;
      v = v > 0.f ? v : 0.2f * v;
      wb = __expf(v - mm) * inv;
    }
    // consume 8 edges; src/weight broadcast from lane (lane&60)|j
#pragma unroll
    for (int j = 0; j < 8; ++j) {
      int sl = (lane & 60) | (j & 3);
      int s = (j < 4) ? __shfl(sa, sl) : __shfl(sb, sl);
      float w = (j < 4) ? __shfl(wa, sl) : __shfl(wb, sl);
      if (e0 + j < end) {  // uniform within the 16-lane group
        const float4* p = (const float4*)&h1[(size_t)s * 128 + c0];
        float4 a = p[0], b = p[1];
        acc0.x += w * a.x; acc0.y += w * a.y; acc0.z += w * a.z; acc0.w += w * a.w;
        acc1.x += w * b.x; acc1.y += w * b.y; acc1.z += w * b.z; acc1.w += w * b.w;
      }
    }
  }
  if (active) {
    float4 bb0 = *(const float4*)&b1[c0];
    float4 bb1 = *(const float4*)&b1[c0 + 4];
    float o[8] = {acc0.x + bb0.x, acc0.y + bb0.y, acc0.z + bb0.z, acc0.w + bb0.w,
                  acc1.x + bb1.x, acc1.y + bb1.y, acc1.z + bb1.z, acc1.w + bb1.w};
#pragma unroll
    for (int j = 0; j < 8; ++j) o[j] = o[j] > 0.f ? o[j] : __expf(o[j]) - 1.f;  // ELU
    *(float4*)&x2[(size_t)node * 128 + c0]     = make_float4(o[0], o[1], o[2], o[3]);
    *(float4*)&x2[(size_t)node * 128 + c0 + 4] = make_float4(o[4], o[5], o[6], o[7]);
  }
}

// ---------------- GEMM2: 4 rows/wave, 16 lanes/row ----------------

__global__ __launch_bounds__(256) void k_gemm2(const float* __restrict__ x2,
                                               const float* __restrict__ W2,
                                               const float* __restrict__ a_src,
                                               const float* __restrict__ a_dst,
                                               float* __restrict__ h2,
                                               float* __restrict__ as2,
                                               float* __restrict__ ad2, int n) {
  int wid = (blockIdx.x * 256 + threadIdx.x) >> 6;
  int lane = threadIdx.x & 63;
  int grp = lane >> 4, l16 = lane & 15;
  int row = wid * 4 + grp;
  if (row >= n) return;
  const float4* xp = (const float4*)&x2[(size_t)row * 128 + l16 * 8];
  float4 xa = xp[0], xb = xp[1];
  const float* wr = &W2[l16 * 8 * 10];
  float acc[10];
#pragma unroll
  for (int c = 0; c < 10; ++c) {
    acc[c] = xa.x * wr[c]      + xa.y * wr[10 + c] + xa.z * wr[20 + c] +
             xa.w * wr[30 + c] + xb.x * wr[40 + c] + xb.y * wr[50 + c] +
             xb.z * wr[60 + c] + xb.w * wr[70 + c];
  }
#pragma unroll
  for (int c = 0; c < 10; ++c) {
#pragma unroll
    for (int d = 1; d < 16; d <<= 1) acc[c] += __shfl_xor(acc[c], d);
  }
  if (l16 == 0) {
    float s = 0.f, ds = 0.f;
#pragma unroll
    for (int c = 0; c < 10; ++c) {
      h2[(size_t)row * 10 + c] = acc[c];
      s += acc[c] * a_src[c];
      ds += acc[c] * a_dst[c];
    }
    as2[row] = s;
    ad2[row] = ds;
  }
}

// ---------------- conv2 aggregation: 4 nodes per wave, 16 lanes per node ----------------

__global__ __launch_bounds__(256) void k_conv2(const int* __restrict__ off,
                                               const int* __restrict__ adj,
                                               const float* __restrict__ h2,
                                               const float* __restrict__ as2,
                                               const float* __restrict__ ad2,
                                               const float* __restrict__ b2,
                                               float* __restrict__ out, int n) {
  int wid = (blockIdx.x * 256 + threadIdx.x) >> 6;
  int lane = threadIdx.x & 63;
  int grp = lane >> 4;
  int l16 = lane & 15;
  int node = wid * 4 + grp;
  bool active = node < n;
  int beg = 0, end = 0;
  float adv = 0.f;
  if (active) {
    beg = off[node];
    end = off[node + 1];
    adv = ad2[node];
  }
  float m = -1e30f, z = 0.f;
  for (int e = beg + l16; e < end; e += 16) {
    int s = adj[e];
    float v = as2[s] + adv;
    v = v > 0.f ? v : 0.2f * v;
    float nm = fmaxf(m, v);
    z = z * __expf(m - nm) + __expf(v - nm);
    m = nm;
  }
#pragma unroll
  for (int d = 1; d < 16; d <<= 1) {
    float om = __shfl_xor(m, d), oz = __shfl_xor(z, d);
    float nm = fmaxf(m, om);
    z = z * __expf(m - nm) + oz * __expf(om - nm);
    m = nm;
  }
  float inv = 1.0f / (z + 1e-16f);
  float acc[10] = {};
  for (int e = beg + l16; e < end; e += 16) {
    int s = adj[e];
    float v = as2[s] + adv;
    v = v > 0.f ? v : 0.2f * v;
    float wgt = __expf(v - m) * inv;
    const float2* hp = (const float2*)&h2[(size_t)s * 10];
    float2 h01 = hp[0], h23 = hp[1], h45 = hp[2], h67 = hp[3], h89 = hp[4];
    acc[0] += wgt * h01.x; acc[1] += wgt * h01.y;
    acc[2] += wgt * h23.x; acc[3] += wgt * h23.y;
    acc[4] += wgt * h45.x; acc[5] += wgt * h45.y;
    acc[6] += wgt * h67.x; acc[7] += wgt * h67.y;
    acc[8] += wgt * h89.x; acc[9] += wgt * h89.y;
  }
#pragma unroll
  for (int c = 0; c < 10; ++c) {
#pragma unroll
    for (int d = 1; d < 16; d <<= 1) acc[c] += __shfl_xor(acc[c], d);
  }
  if (active && l16 == 0) {
#pragma unroll
    for (int c = 0; c < 10; ++c) out[(size_t)node * 10 + c] = acc[c] + b2[c];
  }
}

// ---------------- launch ----------------

extern "C" void kernel_launch(void* const* d_in, const int* in_sizes, int n_in,
                              void* d_out, int out_size, void* d_ws, size_t ws_size,
                              hipStream_t stream) {
  const float* x      = (const float*)d_in[0];
  const int* ei       = (const int*)d_in[1];
  const float* W1     = (const float*)d_in[2];
  const float* a_src1 = (const float*)d_in[3];
  const float* a_dst1 = (const float*)d_in[4];
  const float* b1     = (const float*)d_in[5];
  const float* W2     = (const float*)d_in[6];
  const float* a_src2 = (const float*)d_in[7];
  const float* a_dst2 = (const float*)d_in[8];
  const float* b2     = (const float*)d_in[9];
  float* out = (float*)d_out;
  const int N = in_sizes[0] / 128;
  const int E = in_sizes[1] / 2;

  char* ws = (char*)d_ws;
  size_t o = 0;
  auto alloc = [&](size_t bytes) -> void* {
    void* p = ws + o;
    o += (bytes + 255) & ~(size_t)255;
    return p;
  };
  int* cnt    = (int*)alloc((size_t)N * 4);
  int* cursor = (int*)alloc((size_t)N * 4);
  int* offs   = (int*)alloc((size_t)(N + 1) * 4);
  int* bsum   = (int*)alloc(1024 * 4);
  int* adj    = (int*)alloc((size_t)(E + N) * 4);
  float* h1   = (float*)alloc((size_t)N * 128 * 4);
  float* a_s1 = (float*)alloc((size_t)N * 4 * 4);
  float* a_d1 = (float*)alloc((size_t)N * 4 * 4);
  float* x2   = (float*)alloc((size_t)N * 128 * 4);
  float* h2   = (float*)alloc((size_t)N * 10 * 4);
  float* a_s2 = (float*)alloc((size_t)N * 4);
  float* a_d2 = (float*)alloc((size_t)N * 4);

  int nb = (N + 1023) / 1024;
  k_init<<<(N + 255) / 256, 256, 0, stream>>>(cnt, cursor, N);
  k_count<<<(E + 255) / 256, 256, 0, stream>>>(ei, cnt, E);
  k_bsum<<<nb, 1024, 0, stream>>>(cnt, bsum, N);
  k_scanb<<<1, 64, 0, stream>>>(bsum, offs, nb, N);
  k_scanc<<<nb, 1024, 0, stream>>>(cnt, bsum, offs, N);
  k_scatter<<<(E + N + 255) / 256, 256, 0, stream>>>(ei, offs, cursor, adj, E, N);
  int g1 = (N + 63) / 64;  // one block per 64-row tile
  k_gemm1<<<g1, 256, 0, stream>>>(x, W1, a_src1, a_dst1, h1, a_s1, a_d1, N);
  k_conv1<<<(N + 15) / 16, 256, 0, stream>>>(offs, adj, h1, a_s1, a_d1, b1, x2, N);
  k_gemm2<<<(N + 15) / 16, 256, 0, stream>>>(x2, W2, a_src2, a_dst2, h2, a_s2, a_d2, N);
  k_conv2<<<(N + 15) / 16, 256, 0, stream>>>(offs, adj, h2, a_s2, a_d2, b2, out, N);
}

// Round 6
// 224.964 us; speedup vs baseline: 3.6783x; 1.1055x over previous
//
#include <hip/hip_runtime.h>
#include <hip/hip_bf16.h>
#include <cstdint>

// ---------------- CSR build ----------------
// NOTE: harness passes integer inputs as int32.

__global__ __launch_bounds__(256) void k_init(int* cnt, int* cursor, int n) {
  int i = blockIdx.x * 256 + threadIdx.x;
  if (i < n) { cnt[i] = 1; cursor[i] = 0; }  // cnt starts at 1 for the self-loop
}

__global__ __launch_bounds__(256) void k_count(const int* __restrict__ ei,
                                               int* __restrict__ cnt, int E) {
  int e = blockIdx.x * 256 + threadIdx.x;
  if (e < E) atomicAdd(&cnt[ei[E + e]], 1);
}

__global__ __launch_bounds__(1024) void k_bsum(const int* __restrict__ cnt,
                                               int* __restrict__ bsum, int n) {
  __shared__ int ws_[16];
  int i = blockIdx.x * 1024 + threadIdx.x;
  int v = (i < n) ? cnt[i] : 0;
#pragma unroll
  for (int d = 1; d < 64; d <<= 1) v += __shfl_xor(v, d);
  int lane = threadIdx.x & 63, wid = threadIdx.x >> 6;
  if (lane == 0) ws_[wid] = v;
  __syncthreads();
  if (threadIdx.x == 0) {
    int s = 0;
#pragma unroll
    for (int j = 0; j < 16; ++j) s += ws_[j];
    bsum[blockIdx.x] = s;
  }
}

// single-wave exclusive scan of block sums (nb <= 64 for N=50000)
__global__ __launch_bounds__(64) void k_scanb(int* bsum, int* off, int nb, int n) {
  int t = threadIdx.x;
  int v = (t < nb) ? bsum[t] : 0;
  int orig = v;
#pragma unroll
  for (int d = 1; d < 64; d <<= 1) {
    int u = __shfl_up(v, d, 64);
    if (t >= d) v += u;
  }
  if (t < nb) bsum[t] = v - orig;   // exclusive block offset
  if (t == 63) off[n] = v;          // grand total
}

__global__ __launch_bounds__(1024) void k_scanc(const int* __restrict__ cnt,
                                                const int* __restrict__ bsum,
                                                int* __restrict__ off, int n) {
  __shared__ int wsum[16];
  int i = blockIdx.x * 1024 + threadIdx.x;
  int v = (i < n) ? cnt[i] : 0;
  int orig = v;
  int lane = threadIdx.x & 63, wid = threadIdx.x >> 6;
#pragma unroll
  for (int d = 1; d < 64; d <<= 1) {
    int u = __shfl_up(v, d, 64);
    if (lane >= d) v += u;
  }
  if (lane == 63) wsum[wid] = v;
  __syncthreads();
  if (wid == 0) {
    int s = (lane < 16) ? wsum[lane] : 0;
#pragma unroll
    for (int d = 1; d < 16; d <<= 1) {
      int u = __shfl_up(s, d, 64);
      if (lane >= d) s += u;
    }
    if (lane < 16) wsum[lane] = s;
  }
  __syncthreads();
  if (wid > 0) v += wsum[wid - 1];
  if (i < n) off[i] = bsum[blockIdx.x] + v - orig;  // exclusive
}

__global__ __launch_bounds__(256) void k_scatter(const int* __restrict__ ei,
                                                 const int* __restrict__ off,
                                                 int* __restrict__ cursor,
                                                 int* __restrict__ adj, int E, int n) {
  int idx = blockIdx.x * 256 + threadIdx.x;
  if (idx < E) {
    int s = ei[idx];
    int d = ei[E + idx];
    int pos = off[d] + atomicAdd(&cursor[d], 1);
    adj[pos] = s;
  } else if (idx < E + n) {
    int i = idx - E;
    int pos = off[i] + atomicAdd(&cursor[i], 1);
    adj[pos] = i;  // self loop
  }
}

// bf16 pack with round-to-nearest-even
__device__ inline unsigned short f2bf(float f) {
  unsigned u = __float_as_uint(f);
  unsigned r = (u + 0x7FFFu + ((u >> 16) & 1u)) >> 16;
  return (unsigned short)r;
}

// ---------------- GEMM1: h1(bf16) = x @ W1, fused alpha_src/alpha_dst ----------------
// R3-proven inner structure: scalar xs reads, acc[8][4] floats, unroll-8 K loop.
// (R4's float4-xs variant fully unrolled and spilled at VGPR=256 — do not revisit.)

__global__ __launch_bounds__(256) void k_gemm1(const float* __restrict__ x,
                                               const float* __restrict__ W,
                                               const float* __restrict__ a_src,
                                               const float* __restrict__ a_dst,
                                               unsigned short* __restrict__ h1,
                                               float* __restrict__ as1,
                                               float* __restrict__ ad1, int n) {
  __shared__ float xs[64][132];       // 33.8 KB (padded)
  __shared__ float wbuf[32 * 128];    // 16 KB: one 32-row K-chunk of W
  int t = threadIdx.x;
  int tr = t >> 5, tc = t & 31;
  int head = tc >> 3;
  float a_s[4], a_d[4];
#pragma unroll
  for (int ci = 0; ci < 4; ++ci) {
    int dcol = (tc * 4 + ci) & 31;
    a_s[ci] = a_src[head * 32 + dcol];
    a_d[ci] = a_dst[head * 32 + dcol];
  }
  int ntiles = (n + 63) >> 6;
  for (int tile = blockIdx.x; tile < ntiles; tile += gridDim.x) {
    int row0 = tile << 6;
    __syncthreads();
#pragma unroll
    for (int rr = 0; rr < 64; rr += 8) {
      int r = rr + tr;
      int gr = row0 + r;
      float4 v = make_float4(0.f, 0.f, 0.f, 0.f);
      if (gr < n) v = *(const float4*)&x[(size_t)gr * 128 + tc * 4];
      *(float4*)&xs[r][tc * 4] = v;
    }
    float acc[8][4] = {};
#pragma unroll
    for (int kt = 0; kt < 4; ++kt) {
      __syncthreads();
#pragma unroll
      for (int i = t * 4; i < 32 * 128; i += 1024)
        *(float4*)&wbuf[i] = *(const float4*)&W[kt * 32 * 128 + i];
      __syncthreads();
#pragma unroll 8
      for (int k = 0; k < 32; ++k) {
        float4 wv = *(float4*)&wbuf[k * 128 + tc * 4];
#pragma unroll
        for (int ri = 0; ri < 8; ++ri) {
          float xv = xs[tr * 8 + ri][kt * 32 + k];
          acc[ri][0] += xv * wv.x;
          acc[ri][1] += xv * wv.y;
          acc[ri][2] += xv * wv.z;
          acc[ri][3] += xv * wv.w;
        }
      }
    }
#pragma unroll
    for (int ri = 0; ri < 8; ++ri) {
      int gr = row0 + tr * 8 + ri;
      float ps = acc[ri][0] * a_s[0] + acc[ri][1] * a_s[1] +
                 acc[ri][2] * a_s[2] + acc[ri][3] * a_s[3];
      float pd = acc[ri][0] * a_d[0] + acc[ri][1] * a_d[1] +
                 acc[ri][2] * a_d[2] + acc[ri][3] * a_d[3];
      ps += __shfl_xor(ps, 1); ps += __shfl_xor(ps, 2); ps += __shfl_xor(ps, 4);
      pd += __shfl_xor(pd, 1); pd += __shfl_xor(pd, 2); pd += __shfl_xor(pd, 4);
      if (gr < n) {
        ushort4 hv;
        hv.x = f2bf(acc[ri][0]); hv.y = f2bf(acc[ri][1]);
        hv.z = f2bf(acc[ri][2]); hv.w = f2bf(acc[ri][3]);
        *(ushort4*)&h1[(size_t)gr * 128 + tc * 4] = hv;
        if ((tc & 7) == 0) {
          as1[gr * 4 + head] = ps;
          ad1[gr * 4 + head] = pd;
        }
      }
    }
  }
}

// ---------------- conv1 aggregation: 4 nodes/wave, 16 lanes/node, bf16 h1 gather ----
// phase 2: per 16-edge chunk, the 16 lanes (= 4 edges x 4 heads) precompute all
// softmax weights in parallel; consume loop: shfl + one 16B bf16x8 gather + FMA.

__global__ __launch_bounds__(256) void k_conv1(const int* __restrict__ off,
                                               const int* __restrict__ adj,
                                               const unsigned short* __restrict__ h1,
                                               const float* __restrict__ as1,
                                               const float* __restrict__ ad1,
                                               const float* __restrict__ b1,
                                               float* __restrict__ x2, int n) {
  int wid = (blockIdx.x * 256 + threadIdx.x) >> 6;  // global wave id
  int lane = threadIdx.x & 63;
  int grp = lane >> 4;       // node slot within wave
  int l16 = lane & 15;
  int node = wid * 4 + grp;
  bool active = node < n;
  int beg = 0, end = 0;
  float4 adv = make_float4(0.f, 0.f, 0.f, 0.f);
  if (active) {
    beg = off[node];
    end = off[node + 1];
    adv = *(const float4*)&ad1[node * 4];
  }
  // phase 1: online softmax (m,z) per head; lanes l16 stride 16 over edges
  float m0 = -1e30f, m1 = -1e30f, m2 = -1e30f, m3 = -1e30f;
  float z0 = 0.f, z1 = 0.f, z2 = 0.f, z3 = 0.f;
  for (int e = beg + l16; e < end; e += 16) {
    int s = adj[e];
    float4 av = *(const float4*)&as1[s * 4];
    float v, nm;
    v = av.x + adv.x; v = v > 0.f ? v : 0.2f * v;
    nm = fmaxf(m0, v); z0 = z0 * __expf(m0 - nm) + __expf(v - nm); m0 = nm;
    v = av.y + adv.y; v = v > 0.f ? v : 0.2f * v;
    nm = fmaxf(m1, v); z1 = z1 * __expf(m1 - nm) + __expf(v - nm); m1 = nm;
    v = av.z + adv.z; v = v > 0.f ? v : 0.2f * v;
    nm = fmaxf(m2, v); z2 = z2 * __expf(m2 - nm) + __expf(v - nm); m2 = nm;
    v = av.w + adv.w; v = v > 0.f ? v : 0.2f * v;
    nm = fmaxf(m3, v); z3 = z3 * __expf(m3 - nm) + __expf(v - nm); m3 = nm;
  }
#pragma unroll
  for (int d = 1; d < 16; d <<= 1) {  // butterfly within 16-lane group
    float om, oz, nm;
    om = __shfl_xor(m0, d); oz = __shfl_xor(z0, d);
    nm = fmaxf(m0, om); z0 = z0 * __expf(m0 - nm) + oz * __expf(om - nm); m0 = nm;
    om = __shfl_xor(m1, d); oz = __shfl_xor(z1, d);
    nm = fmaxf(m1, om); z1 = z1 * __expf(m1 - nm) + oz * __expf(om - nm); m1 = nm;
    om = __shfl_xor(m2, d); oz = __shfl_xor(z2, d);
    nm = fmaxf(m2, om); z2 = z2 * __expf(m2 - nm) + oz * __expf(om - nm); m2 = nm;
    om = __shfl_xor(m3, d); oz = __shfl_xor(z3, d);
    nm = fmaxf(m3, om); z3 = z3 * __expf(m3 - nm) + oz * __expf(om - nm); m3 = nm;
  }
  // phase 2
  int hh = (l16 >> 2) & 3;   // head for this lane's channels AND its weight-compute slot
  int esub = l16 & 3;        // edge slot within chunk quarter
  float mm  = hh == 0 ? m0 : hh == 1 ? m1 : hh == 2 ? m2 : m3;
  float zz  = hh == 0 ? z0 : hh == 1 ? z1 : hh == 2 ? z2 : z3;
  float adh = hh == 0 ? adv.x : hh == 1 ? adv.y : hh == 2 ? adv.z : adv.w;
  float inv = 1.0f / (zz + 1e-16f);
  int c0 = l16 * 8;  // 8 bf16 channels per lane
  float acc[8] = {};
  for (int e0 = beg; e0 < end; e0 += 16) {
    // 16-wide weight precompute for 4 edge slots at head hh
    int sa = 0, sb = 0, sc = 0, sd = 0;
    float wa = 0.f, wb = 0.f, wc = 0.f, wdd = 0.f;
    int ea = e0 + esub, eb = e0 + 4 + esub, ec = e0 + 8 + esub, ed = e0 + 12 + esub;
    if (ea < end) {
      sa = adj[ea];
      float v = as1[sa * 4 + hh] + adh;
      v = v > 0.f ? v : 0.2f * v;
      wa = __expf(v - mm) * inv;
    }
    if (eb < end) {
      sb = adj[eb];
      float v = as1[sb * 4 + hh] + adh;
      v = v > 0.f ? v : 0.2f * v;
      wb = __expf(v - mm) * inv;
    }
    if (ec < end) {
      sc = adj[ec];
      float v = as1[sc * 4 + hh] + adh;
      v = v > 0.f ? v : 0.2f * v;
      wc = __expf(v - mm) * inv;
    }
    if (ed < end) {
      sd = adj[ed];
      float v = as1[sd * 4 + hh] + adh;
      v = v > 0.f ? v : 0.2f * v;
      wdd = __expf(v - mm) * inv;
    }
    // consume 16 edges; src/weight broadcast from lane (lane&60)|(j&3)
#pragma unroll
    for (int j = 0; j < 16; ++j) {
      int sl = (lane & 60) | (j & 3);
      int s = (j < 4) ? __shfl(sa, sl) : (j < 8) ? __shfl(sb, sl)
             : (j < 12) ? __shfl(sc, sl) : __shfl(sd, sl);
      float w = (j < 4) ? __shfl(wa, sl) : (j < 8) ? __shfl(wb, sl)
             : (j < 12) ? __shfl(wc, sl) : __shfl(wdd, sl);
      if (e0 + j < end) {  // uniform within the 16-lane group
        uint4 q = *(const uint4*)&h1[(size_t)s * 128 + c0];
        acc[0] += w * __uint_as_float(q.x << 16);
        acc[1] += w * __uint_as_float(q.x & 0xffff0000u);
        acc[2] += w * __uint_as_float(q.y << 16);
        acc[3] += w * __uint_as_float(q.y & 0xffff0000u);
        acc[4] += w * __uint_as_float(q.z << 16);
        acc[5] += w * __uint_as_float(q.z & 0xffff0000u);
        acc[6] += w * __uint_as_float(q.w << 16);
        acc[7] += w * __uint_as_float(q.w & 0xffff0000u);
      }
    }
  }
  if (active) {
    float o[8];
#pragma unroll
    for (int j = 0; j < 8; ++j) {
      float v = acc[j] + b1[c0 + j];
      o[j] = v > 0.f ? v : __expf(v) - 1.f;  // ELU fused
    }
    *(float4*)&x2[(size_t)node * 128 + c0]     = make_float4(o[0], o[1], o[2], o[3]);
    *(float4*)&x2[(size_t)node * 128 + c0 + 4] = make_float4(o[4], o[5], o[6], o[7]);
  }
}

// ---------------- GEMM2: 4 rows/wave, 16 lanes/row ----------------

__global__ __launch_bounds__(256) void k_gemm2(const float* __restrict__ x2,
                                               const float* __restrict__ W2,
                                               const float* __restrict__ a_src,
                                               const float* __restrict__ a_dst,
                                               float* __restrict__ h2,
                                               float* __restrict__ as2,
                                               float* __restrict__ ad2, int n) {
  int wid = (blockIdx.x * 256 + threadIdx.x) >> 6;
  int lane = threadIdx.x & 63;
  int grp = lane >> 4, l16 = lane & 15;
  int row = wid * 4 + grp;
  if (row >= n) return;
  const float4* xp = (const float4*)&x2[(size_t)row * 128 + l16 * 8];
  float4 xa = xp[0], xb = xp[1];
  const float* wr = &W2[l16 * 8 * 10];
  float acc[10];
#pragma unroll
  for (int c = 0; c < 10; ++c) {
    acc[c] = xa.x * wr[c]      + xa.y * wr[10 + c] + xa.z * wr[20 + c] +
             xa.w * wr[30 + c] + xb.x * wr[40 + c] + xb.y * wr[50 + c] +
             xb.z * wr[60 + c] + xb.w * wr[70 + c];
  }
#pragma unroll
  for (int c = 0; c < 10; ++c) {
#pragma unroll
    for (int d = 1; d < 16; d <<= 1) acc[c] += __shfl_xor(acc[c], d);
  }
  if (l16 == 0) {
    float s = 0.f, ds = 0.f;
#pragma unroll
    for (int c = 0; c < 10; ++c) {
      h2[(size_t)row * 10 + c] = acc[c];
      s += acc[c] * a_src[c];
      ds += acc[c] * a_dst[c];
    }
    as2[row] = s;
    ad2[row] = ds;
  }
}

// ---------------- conv2 aggregation: 4 nodes per wave, 16 lanes per node ----------------

__global__ __launch_bounds__(256) void k_conv2(const int* __restrict__ off,
                                               const int* __restrict__ adj,
                                               const float* __restrict__ h2,
                                               const float* __restrict__ as2,
                                               const float* __restrict__ ad2,
                                               const float* __restrict__ b2,
                                               float* __restrict__ out, int n) {
  int wid = (blockIdx.x * 256 + threadIdx.x) >> 6;
  int lane = threadIdx.x & 63;
  int grp = lane >> 4;
  int l16 = lane & 15;
  int node = wid * 4 + grp;
  bool active = node < n;
  int beg = 0, end = 0;
  float adv = 0.f;
  if (active) {
    beg = off[node];
    end = off[node + 1];
    adv = ad2[node];
  }
  float m = -1e30f, z = 0.f;
  for (int e = beg + l16; e < end; e += 16) {
    int s = adj[e];
    float v = as2[s] + adv;
    v = v > 0.f ? v : 0.2f * v;
    float nm = fmaxf(m, v);
    z = z * __expf(m - nm) + __expf(v - nm);
    m = nm;
  }
#pragma unroll
  for (int d = 1; d < 16; d <<= 1) {
    float om = __shfl_xor(m, d), oz = __shfl_xor(z, d);
    float nm = fmaxf(m, om);
    z = z * __expf(m - nm) + oz * __expf(om - nm);
    m = nm;
  }
  float inv = 1.0f / (z + 1e-16f);
  float acc[10] = {};
  for (int e = beg + l16; e < end; e += 16) {
    int s = adj[e];
    float v = as2[s] + adv;
    v = v > 0.f ? v : 0.2f * v;
    float wgt = __expf(v - m) * inv;
    const float2* hp = (const float2*)&h2[(size_t)s * 10];
    float2 h01 = hp[0], h23 = hp[1], h45 = hp[2], h67 = hp[3], h89 = hp[4];
    acc[0] += wgt * h01.x; acc[1] += wgt * h01.y;
    acc[2] += wgt * h23.x; acc[3] += wgt * h23.y;
    acc[4] += wgt * h45.x; acc[5] += wgt * h45.y;
    acc[6] += wgt * h67.x; acc[7] += wgt * h67.y;
    acc[8] += wgt * h89.x; acc[9] += wgt * h89.y;
  }
#pragma unroll
  for (int c = 0; c < 10; ++c) {
#pragma unroll
    for (int d = 1; d < 16; d <<= 1) acc[c] += __shfl_xor(acc[c], d);
  }
  if (active && l16 == 0) {
#pragma unroll
    for (int c = 0; c < 10; ++c) out[(size_t)node * 10 + c] = acc[c] + b2[c];
  }
}

// ---------------- launch ----------------

extern "C" void kernel_launch(void* const* d_in, const int* in_sizes, int n_in,
                              void* d_out, int out_size, void* d_ws, size_t ws_size,
                              hipStream_t stream) {
  const float* x      = (const float*)d_in[0];
  const int* ei       = (const int*)d_in[1];
  const float* W1     = (const float*)d_in[2];
  const float* a_src1 = (const float*)d_in[3];
  const float* a_dst1 = (const float*)d_in[4];
  const float* b1     = (const float*)d_in[5];
  const float* W2     = (const float*)d_in[6];
  const float* a_src2 = (const float*)d_in[7];
  const float* a_dst2 = (const float*)d_in[8];
  const float* b2     = (const float*)d_in[9];
  float* out = (float*)d_out;
  const int N = in_sizes[0] / 128;
  const int E = in_sizes[1] / 2;

  char* ws = (char*)d_ws;
  size_t o = 0;
  auto alloc = [&](size_t bytes) -> void* {
    void* p = ws + o;
    o += (bytes + 255) & ~(size_t)255;
    return p;
  };
  int* cnt    = (int*)alloc((size_t)N * 4);
  int* cursor = (int*)alloc((size_t)N * 4);
  int* offs   = (int*)alloc((size_t)(N + 1) * 4);
  int* bsum   = (int*)alloc(1024 * 4);
  int* adj    = (int*)alloc((size_t)(E + N) * 4);
  unsigned short* h1 = (unsigned short*)alloc((size_t)N * 128 * 2);  // bf16
  float* a_s1 = (float*)alloc((size_t)N * 4 * 4);
  float* a_d1 = (float*)alloc((size_t)N * 4 * 4);
  float* x2   = (float*)alloc((size_t)N * 128 * 4);
  float* h2   = (float*)alloc((size_t)N * 10 * 4);
  float* a_s2 = (float*)alloc((size_t)N * 4);
  float* a_d2 = (float*)alloc((size_t)N * 4);

  int nb = (N + 1023) / 1024;
  k_init<<<(N + 255) / 256, 256, 0, stream>>>(cnt, cursor, N);
  k_count<<<(E + 255) / 256, 256, 0, stream>>>(ei, cnt, E);
  k_bsum<<<nb, 1024, 0, stream>>>(cnt, bsum, N);
  k_scanb<<<1, 64, 0, stream>>>(bsum, offs, nb, N);
  k_scanc<<<nb, 1024, 0, stream>>>(cnt, bsum, offs, N);
  k_scatter<<<(E + N + 255) / 256, 256, 0, stream>>>(ei, offs, cursor, adj, E, N);
  int g1 = (N + 63) / 64;  // one block per 64-row tile
  k_gemm1<<<g1, 256, 0, stream>>>(x, W1, a_src1, a_dst1, h1, a_s1, a_d1, N);
  k_conv1<<<(N + 15) / 16, 256, 0, stream>>>(offs, adj, h1, a_s1, a_d1, b1, x2, N);
  k_gemm2<<<(N + 15) / 16, 256, 0, stream>>>(x2, W2, a_src2, a_dst2, h2, a_s2, a_d2, N);
  k_conv2<<<(N + 15) / 16, 256, 0, stream>>>(offs, adj, h2, a_s2, a_d2, b2, out, N);
}

// Round 7
// 190.147 us; speedup vs baseline: 4.3518x; 1.1831x over previous
//
#include <hip/hip_runtime.h>
#include <hip/hip_bf16.h>
#include <cstdint>

// ---------------- CSR build ----------------
// NOTE: harness passes integer inputs as int32.
// cnt is memset to 0; node i's segment length = cnt[i]+1 (self-loop at slot off[i]).

__global__ __launch_bounds__(256) void k_count(const int* __restrict__ ei,
                                               int* __restrict__ cnt,
                                               int* __restrict__ rank, int E) {
  int e = blockIdx.x * 256 + threadIdx.x;
  if (e < E) rank[e] = atomicAdd(&cnt[ei[E + e]], 1);
}

__global__ __launch_bounds__(1024) void k_bsum(const int* __restrict__ cnt,
                                               int* __restrict__ bsum, int n) {
  __shared__ int ws_[16];
  int i = blockIdx.x * 1024 + threadIdx.x;
  int v = (i < n) ? cnt[i] + 1 : 0;   // +1: self-loop
#pragma unroll
  for (int d = 1; d < 64; d <<= 1) v += __shfl_xor(v, d);
  int lane = threadIdx.x & 63, wid = threadIdx.x >> 6;
  if (lane == 0) ws_[wid] = v;
  __syncthreads();
  if (threadIdx.x == 0) {
    int s = 0;
#pragma unroll
    for (int j = 0; j < 16; ++j) s += ws_[j];
    bsum[blockIdx.x] = s;
  }
}

// single-wave exclusive scan of block sums (nb <= 64 for N=50000)
__global__ __launch_bounds__(64) void k_scanb(int* bsum, int* off, int nb, int n) {
  int t = threadIdx.x;
  int v = (t < nb) ? bsum[t] : 0;
  int orig = v;
#pragma unroll
  for (int d = 1; d < 64; d <<= 1) {
    int u = __shfl_up(v, d, 64);
    if (t >= d) v += u;
  }
  if (t < nb) bsum[t] = v - orig;   // exclusive block offset
  if (t == 63) off[n] = v;          // grand total (= E + n)
}

__global__ __launch_bounds__(1024) void k_scanc(const int* __restrict__ cnt,
                                                const int* __restrict__ bsum,
                                                int* __restrict__ off, int n) {
  __shared__ int wsum[16];
  int i = blockIdx.x * 1024 + threadIdx.x;
  int v = (i < n) ? cnt[i] + 1 : 0;   // +1: self-loop
  int orig = v;
  int lane = threadIdx.x & 63, wid = threadIdx.x >> 6;
#pragma unroll
  for (int d = 1; d < 64; d <<= 1) {
    int u = __shfl_up(v, d, 64);
    if (lane >= d) v += u;
  }
  if (lane == 63) wsum[wid] = v;
  __syncthreads();
  if (wid == 0) {
    int s = (lane < 16) ? wsum[lane] : 0;
#pragma unroll
    for (int d = 1; d < 16; d <<= 1) {
      int u = __shfl_up(s, d, 64);
      if (lane >= d) s += u;
    }
    if (lane < 16) wsum[lane] = s;
  }
  __syncthreads();
  if (wid > 0) v += wsum[wid - 1];
  if (i < n) off[i] = bsum[blockIdx.x] + v - orig;  // exclusive
}

// atomic-free scatter: pos = off[dst] + 1 + rank[e]; self-loop at off[i]
__global__ __launch_bounds__(256) void k_scatter(const int* __restrict__ ei,
                                                 const int* __restrict__ off,
                                                 const int* __restrict__ rank,
                                                 int* __restrict__ adj, int E, int n) {
  int idx = blockIdx.x * 256 + threadIdx.x;
  if (idx < E) {
    int s = ei[idx];
    int d = ei[E + idx];
    adj[off[d] + 1 + rank[idx]] = s;
  } else if (idx < E + n) {
    int i = idx - E;
    adj[off[i]] = i;  // self loop
  }
}

// bf16 pack with round-to-nearest-even
__device__ inline unsigned short f2bf(float f) {
  unsigned u = __float_as_uint(f);
  unsigned r = (u + 0x7FFFu + ((u >> 16) & 1u)) >> 16;
  return (unsigned short)r;
}

// ---------------- GEMM1: h1(bf16) = x @ W1, fused alpha_src/alpha_dst ----------------
// R3-proven inner structure: scalar xs reads, acc[8][4] floats, unroll-8 K loop.
// (R4's float4-xs variant fully unrolled and spilled at VGPR=256 — do not revisit.)

__global__ __launch_bounds__(256) void k_gemm1(const float* __restrict__ x,
                                               const float* __restrict__ W,
                                               const float* __restrict__ a_src,
                                               const float* __restrict__ a_dst,
                                               unsigned short* __restrict__ h1,
                                               float* __restrict__ as1,
                                               float* __restrict__ ad1, int n) {
  __shared__ float xs[64][132];       // 33.8 KB (padded)
  __shared__ float wbuf[32 * 128];    // 16 KB: one 32-row K-chunk of W
  int t = threadIdx.x;
  int tr = t >> 5, tc = t & 31;
  int head = tc >> 3;
  float a_s[4], a_d[4];
#pragma unroll
  for (int ci = 0; ci < 4; ++ci) {
    int dcol = (tc * 4 + ci) & 31;
    a_s[ci] = a_src[head * 32 + dcol];
    a_d[ci] = a_dst[head * 32 + dcol];
  }
  int ntiles = (n + 63) >> 6;
  for (int tile = blockIdx.x; tile < ntiles; tile += gridDim.x) {
    int row0 = tile << 6;
    __syncthreads();
#pragma unroll
    for (int rr = 0; rr < 64; rr += 8) {
      int r = rr + tr;
      int gr = row0 + r;
      float4 v = make_float4(0.f, 0.f, 0.f, 0.f);
      if (gr < n) v = *(const float4*)&x[(size_t)gr * 128 + tc * 4];
      *(float4*)&xs[r][tc * 4] = v;
    }
    float acc[8][4] = {};
#pragma unroll
    for (int kt = 0; kt < 4; ++kt) {
      __syncthreads();
#pragma unroll
      for (int i = t * 4; i < 32 * 128; i += 1024)
        *(float4*)&wbuf[i] = *(const float4*)&W[kt * 32 * 128 + i];
      __syncthreads();
#pragma unroll 8
      for (int k = 0; k < 32; ++k) {
        float4 wv = *(float4*)&wbuf[k * 128 + tc * 4];
#pragma unroll
        for (int ri = 0; ri < 8; ++ri) {
          float xv = xs[tr * 8 + ri][kt * 32 + k];
          acc[ri][0] += xv * wv.x;
          acc[ri][1] += xv * wv.y;
          acc[ri][2] += xv * wv.z;
          acc[ri][3] += xv * wv.w;
        }
      }
    }
#pragma unroll
    for (int ri = 0; ri < 8; ++ri) {
      int gr = row0 + tr * 8 + ri;
      float ps = acc[ri][0] * a_s[0] + acc[ri][1] * a_s[1] +
                 acc[ri][2] * a_s[2] + acc[ri][3] * a_s[3];
      float pd = acc[ri][0] * a_d[0] + acc[ri][1] * a_d[1] +
                 acc[ri][2] * a_d[2] + acc[ri][3] * a_d[3];
      ps += __shfl_xor(ps, 1); ps += __shfl_xor(ps, 2); ps += __shfl_xor(ps, 4);
      pd += __shfl_xor(pd, 1); pd += __shfl_xor(pd, 2); pd += __shfl_xor(pd, 4);
      if (gr < n) {
        ushort4 hv;
        hv.x = f2bf(acc[ri][0]); hv.y = f2bf(acc[ri][1]);
        hv.z = f2bf(acc[ri][2]); hv.w = f2bf(acc[ri][3]);
        *(ushort4*)&h1[(size_t)gr * 128 + tc * 4] = hv;
        if ((tc & 7) == 0) {
          as1[gr * 4 + head] = ps;
          ad1[gr * 4 + head] = pd;
        }
      }
    }
  }
}

// ---------------- conv1 aggregation: 4 nodes/wave, 16 lanes/node, bf16 h1 gather ----
// phase 2: per 16-edge chunk, the 16 lanes (= 4 edges x 4 heads) precompute all
// softmax weights in parallel; consume loop: shfl + one 16B bf16x8 gather + FMA.

__global__ __launch_bounds__(256) void k_conv1(const int* __restrict__ off,
                                               const int* __restrict__ adj,
                                               const unsigned short* __restrict__ h1,
                                               const float* __restrict__ as1,
                                               const float* __restrict__ ad1,
                                               const float* __restrict__ b1,
                                               float* __restrict__ x2, int n) {
  int wid = (blockIdx.x * 256 + threadIdx.x) >> 6;  // global wave id
  int lane = threadIdx.x & 63;
  int grp = lane >> 4;       // node slot within wave
  int l16 = lane & 15;
  int node = wid * 4 + grp;
  bool active = node < n;
  int beg = 0, end = 0;
  float4 adv = make_float4(0.f, 0.f, 0.f, 0.f);
  if (active) {
    beg = off[node];
    end = off[node + 1];
    adv = *(const float4*)&ad1[node * 4];
  }
  // phase 1: online softmax (m,z) per head; lanes l16 stride 16 over edges
  float m0 = -1e30f, m1 = -1e30f, m2 = -1e30f, m3 = -1e30f;
  float z0 = 0.f, z1 = 0.f, z2 = 0.f, z3 = 0.f;
  for (int e = beg + l16; e < end; e += 16) {
    int s = adj[e];
    float4 av = *(const float4*)&as1[s * 4];
    float v, nm;
    v = av.x + adv.x; v = v > 0.f ? v : 0.2f * v;
    nm = fmaxf(m0, v); z0 = z0 * __expf(m0 - nm) + __expf(v - nm); m0 = nm;
    v = av.y + adv.y; v = v > 0.f ? v : 0.2f * v;
    nm = fmaxf(m1, v); z1 = z1 * __expf(m1 - nm) + __expf(v - nm); m1 = nm;
    v = av.z + adv.z; v = v > 0.f ? v : 0.2f * v;
    nm = fmaxf(m2, v); z2 = z2 * __expf(m2 - nm) + __expf(v - nm); m2 = nm;
    v = av.w + adv.w; v = v > 0.f ? v : 0.2f * v;
    nm = fmaxf(m3, v); z3 = z3 * __expf(m3 - nm) + __expf(v - nm); m3 = nm;
  }
#pragma unroll
  for (int d = 1; d < 16; d <<= 1) {  // butterfly within 16-lane group
    float om, oz, nm;
    om = __shfl_xor(m0, d); oz = __shfl_xor(z0, d);
    nm = fmaxf(m0, om); z0 = z0 * __expf(m0 - nm) + oz * __expf(om - nm); m0 = nm;
    om = __shfl_xor(m1, d); oz = __shfl_xor(z1, d);
    nm = fmaxf(m1, om); z1 = z1 * __expf(m1 - nm) + oz * __expf(om - nm); m1 = nm;
    om = __shfl_xor(m2, d); oz = __shfl_xor(z2, d);
    nm = fmaxf(m2, om); z2 = z2 * __expf(m2 - nm) + oz * __expf(om - nm); m2 = nm;
    om = __shfl_xor(m3, d); oz = __shfl_xor(z3, d);
    nm = fmaxf(m3, om); z3 = z3 * __expf(m3 - nm) + oz * __expf(om - nm); m3 = nm;
  }
  // phase 2
  int hh = (l16 >> 2) & 3;   // head for this lane's channels AND its weight-compute slot
  int esub = l16 & 3;        // edge slot within chunk quarter
  float mm  = hh == 0 ? m0 : hh == 1 ? m1 : hh == 2 ? m2 : m3;
  float zz  = hh == 0 ? z0 : hh == 1 ? z1 : hh == 2 ? z2 : z3;
  float adh = hh == 0 ? adv.x : hh == 1 ? adv.y : hh == 2 ? adv.z : adv.w;
  float inv = 1.0f / (zz + 1e-16f);
  int c0 = l16 * 8;  // 8 bf16 channels per lane
  float acc[8] = {};
  for (int e0 = beg; e0 < end; e0 += 16) {
    // 16-wide weight precompute for 4 edge slots at head hh
    int sa = 0, sb = 0, sc = 0, sd = 0;
    float wa = 0.f, wb = 0.f, wc = 0.f, wdd = 0.f;
    int ea = e0 + esub, eb = e0 + 4 + esub, ec = e0 + 8 + esub, ed = e0 + 12 + esub;
    if (ea < end) {
      sa = adj[ea];
      float v = as1[sa * 4 + hh] + adh;
      v = v > 0.f ? v : 0.2f * v;
      wa = __expf(v - mm) * inv;
    }
    if (eb < end) {
      sb = adj[eb];
      float v = as1[sb * 4 + hh] + adh;
      v = v > 0.f ? v : 0.2f * v;
      wb = __expf(v - mm) * inv;
    }
    if (ec < end) {
      sc = adj[ec];
      float v = as1[sc * 4 + hh] + adh;
      v = v > 0.f ? v : 0.2f * v;
      wc = __expf(v - mm) * inv;
    }
    if (ed < end) {
      sd = adj[ed];
      float v = as1[sd * 4 + hh] + adh;
      v = v > 0.f ? v : 0.2f * v;
      wdd = __expf(v - mm) * inv;
    }
    // consume 16 edges; src/weight broadcast from lane (lane&60)|(j&3)
#pragma unroll
    for (int j = 0; j < 16; ++j) {
      int sl = (lane & 60) | (j & 3);
      int s = (j < 4) ? __shfl(sa, sl) : (j < 8) ? __shfl(sb, sl)
             : (j < 12) ? __shfl(sc, sl) : __shfl(sd, sl);
      float w = (j < 4) ? __shfl(wa, sl) : (j < 8) ? __shfl(wb, sl)
             : (j < 12) ? __shfl(wc, sl) : __shfl(wdd, sl);
      if (e0 + j < end) {  // uniform within the 16-lane group
        uint4 q = *(const uint4*)&h1[(size_t)s * 128 + c0];
        acc[0] += w * __uint_as_float(q.x << 16);
        acc[1] += w * __uint_as_float(q.x & 0xffff0000u);
        acc[2] += w * __uint_as_float(q.y << 16);
        acc[3] += w * __uint_as_float(q.y & 0xffff0000u);
        acc[4] += w * __uint_as_float(q.z << 16);
        acc[5] += w * __uint_as_float(q.z & 0xffff0000u);
        acc[6] += w * __uint_as_float(q.w << 16);
        acc[7] += w * __uint_as_float(q.w & 0xffff0000u);
      }
    }
  }
  if (active) {
    float o[8];
#pragma unroll
    for (int j = 0; j < 8; ++j) {
      float v = acc[j] + b1[c0 + j];
      o[j] = v > 0.f ? v : __expf(v) - 1.f;  // ELU fused
    }
    *(float4*)&x2[(size_t)node * 128 + c0]     = make_float4(o[0], o[1], o[2], o[3]);
    *(float4*)&x2[(size_t)node * 128 + c0 + 4] = make_float4(o[4], o[5], o[6], o[7]);
  }
}

// ---------------- GEMM2: 4 rows/wave, 16 lanes/row ----------------

__global__ __launch_bounds__(256) void k_gemm2(const float* __restrict__ x2,
                                               const float* __restrict__ W2,
                                               const float* __restrict__ a_src,
                                               const float* __restrict__ a_dst,
                                               float* __restrict__ h2,
                                               float* __restrict__ as2,
                                               float* __restrict__ ad2, int n) {
  int wid = (blockIdx.x * 256 + threadIdx.x) >> 6;
  int lane = threadIdx.x & 63;
  int grp = lane >> 4, l16 = lane & 15;
  int row = wid * 4 + grp;
  if (row >= n) return;
  const float4* xp = (const float4*)&x2[(size_t)row * 128 + l16 * 8];
  float4 xa = xp[0], xb = xp[1];
  const float* wr = &W2[l16 * 8 * 10];
  float acc[10];
#pragma unroll
  for (int c = 0; c < 10; ++c) {
    acc[c] = xa.x * wr[c]      + xa.y * wr[10 + c] + xa.z * wr[20 + c] +
             xa.w * wr[30 + c] + xb.x * wr[40 + c] + xb.y * wr[50 + c] +
             xb.z * wr[60 + c] + xb.w * wr[70 + c];
  }
#pragma unroll
  for (int c = 0; c < 10; ++c) {
#pragma unroll
    for (int d = 1; d < 16; d <<= 1) acc[c] += __shfl_xor(acc[c], d);
  }
  if (l16 == 0) {
    float s = 0.f, ds = 0.f;
#pragma unroll
    for (int c = 0; c < 10; ++c) {
      h2[(size_t)row * 10 + c] = acc[c];
      s += acc[c] * a_src[c];
      ds += acc[c] * a_dst[c];
    }
    as2[row] = s;
    ad2[row] = ds;
  }
}

// ---------------- conv2 aggregation: 4 nodes per wave, 16 lanes per node ----------------

__global__ __launch_bounds__(256) void k_conv2(const int* __restrict__ off,
                                               const int* __restrict__ adj,
                                               const float* __restrict__ h2,
                                               const float* __restrict__ as2,
                                               const float* __restrict__ ad2,
                                               const float* __restrict__ b2,
                                               float* __restrict__ out, int n) {
  int wid = (blockIdx.x * 256 + threadIdx.x) >> 6;
  int lane = threadIdx.x & 63;
  int grp = lane >> 4;
  int l16 = lane & 15;
  int node = wid * 4 + grp;
  bool active = node < n;
  int beg = 0, end = 0;
  float adv = 0.f;
  if (active) {
    beg = off[node];
    end = off[node + 1];
    adv = ad2[node];
  }
  float m = -1e30f, z = 0.f;
  for (int e = beg + l16; e < end; e += 16) {
    int s = adj[e];
    float v = as2[s] + adv;
    v = v > 0.f ? v : 0.2f * v;
    float nm = fmaxf(m, v);
    z = z * __expf(m - nm) + __expf(v - nm);
    m = nm;
  }
#pragma unroll
  for (int d = 1; d < 16; d <<= 1) {
    float om = __shfl_xor(m, d), oz = __shfl_xor(z, d);
    float nm = fmaxf(m, om);
    z = z * __expf(m - nm) + oz * __expf(om - nm);
    m = nm;
  }
  float inv = 1.0f / (z + 1e-16f);
  float acc[10] = {};
  for (int e = beg + l16; e < end; e += 16) {
    int s = adj[e];
    float v = as2[s] + adv;
    v = v > 0.f ? v : 0.2f * v;
    float wgt = __expf(v - m) * inv;
    const float2* hp = (const float2*)&h2[(size_t)s * 10];
    float2 h01 = hp[0], h23 = hp[1], h45 = hp[2], h67 = hp[3], h89 = hp[4];
    acc[0] += wgt * h01.x; acc[1] += wgt * h01.y;
    acc[2] += wgt * h23.x; acc[3] += wgt * h23.y;
    acc[4] += wgt * h45.x; acc[5] += wgt * h45.y;
    acc[6] += wgt * h67.x; acc[7] += wgt * h67.y;
    acc[8] += wgt * h89.x; acc[9] += wgt * h89.y;
  }
#pragma unroll
  for (int c = 0; c < 10; ++c) {
#pragma unroll
    for (int d = 1; d < 16; d <<= 1) acc[c] += __shfl_xor(acc[c], d);
  }
  if (active && l16 == 0) {
#pragma unroll
    for (int c = 0; c < 10; ++c) out[(size_t)node * 10 + c] = acc[c] + b2[c];
  }
}

// ---------------- launch ----------------

extern "C" void kernel_launch(void* const* d_in, const int* in_sizes, int n_in,
                              void* d_out, int out_size, void* d_ws, size_t ws_size,
                              hipStream_t stream) {
  const float* x      = (const float*)d_in[0];
  const int* ei       = (const int*)d_in[1];
  const float* W1     = (const float*)d_in[2];
  const float* a_src1 = (const float*)d_in[3];
  const float* a_dst1 = (const float*)d_in[4];
  const float* b1     = (const float*)d_in[5];
  const float* W2     = (const float*)d_in[6];
  const float* a_src2 = (const float*)d_in[7];
  const float* a_dst2 = (const float*)d_in[8];
  const float* b2     = (const float*)d_in[9];
  float* out = (float*)d_out;
  const int N = in_sizes[0] / 128;
  const int E = in_sizes[1] / 2;

  char* ws = (char*)d_ws;
  size_t o = 0;
  auto alloc = [&](size_t bytes) -> void* {
    void* p = ws + o;
    o += (bytes + 255) & ~(size_t)255;
    return p;
  };
  int* cnt    = (int*)alloc((size_t)N * 4);
  int* rank_  = (int*)alloc((size_t)E * 4);
  int* offs   = (int*)alloc((size_t)(N + 1) * 4);
  int* bsum   = (int*)alloc(1024 * 4);
  int* adj    = (int*)alloc((size_t)(E + N) * 4);
  unsigned short* h1 = (unsigned short*)alloc((size_t)N * 128 * 2);  // bf16
  float* a_s1 = (float*)alloc((size_t)N * 4 * 4);
  float* a_d1 = (float*)alloc((size_t)N * 4 * 4);
  float* x2   = (float*)alloc((size_t)N * 128 * 4);
  float* h2   = (float*)alloc((size_t)N * 10 * 4);
  float* a_s2 = (float*)alloc((size_t)N * 4);
  float* a_d2 = (float*)alloc((size_t)N * 4);

  int nb = (N + 1023) / 1024;
  hipMemsetAsync(cnt, 0, (size_t)N * 4, stream);
  k_count<<<(E + 255) / 256, 256, 0, stream>>>(ei, cnt, rank_, E);
  k_bsum<<<nb, 1024, 0, stream>>>(cnt, bsum, N);
  k_scanb<<<1, 64, 0, stream>>>(bsum, offs, nb, N);
  k_scanc<<<nb, 1024, 0, stream>>>(cnt, bsum, offs, N);
  k_scatter<<<(E + N + 255) / 256, 256, 0, stream>>>(ei, offs, rank_, adj, E, N);
  int g1 = (N + 63) / 64;  // one block per 64-row tile
  k_gemm1<<<g1, 256, 0, stream>>>(x, W1, a_src1, a_dst1, h1, a_s1, a_d1, N);
  k_conv1<<<(N + 15) / 16, 256, 0, stream>>>(offs, adj, h1, a_s1, a_d1, b1, x2, N);
  k_gemm2<<<(N + 15) / 16, 256, 0, stream>>>(x2, W2, a_src2, a_dst2, h2, a_s2, a_d2, N);
  k_conv2<<<(N + 15) / 16, 256, 0, stream>>>(offs, adj, h2, a_s2, a_d2, b2, out, N);
}